// Round 5
// baseline (293.437 us; speedup 1.0000x reference)
//
#include <hip/hip_runtime.h>
#include <stdint.h>

#define N_NODES 20000
#define N_EDGES 320000
#define K_MIX 5
#define IN_F 256
#define OUT_F 128
#define NT 11              /* 1 + 2K column tiles of 128 */

typedef __attribute__((ext_vector_type(8))) short short8;
typedef __attribute__((ext_vector_type(4))) float floatx4;

__device__ __forceinline__ unsigned short f2bf(float f) {
  union { float f; unsigned int i; } v;
  v.f = f;
  unsigned int x = v.i;
  unsigned int r = (x + 0x7fffu + ((x >> 16) & 1u)) >> 16;
  return (unsigned short)r;
}

__device__ __forceinline__ float exrelu(float mu, float sig) {
  // E[relu(X)], X ~ N(mu, sig) (sig is the variance). sig==0 -> relu(mu).
  if (sig < 1e-30f) return fmaxf(mu, 0.f);
  float ss = sqrtf(sig);
  float w = mu / ss;
  return ss * (expf(-0.5f * w * w) * 0.3989422804014327f +
               0.5f * w * (1.f + erff(w * 0.70710678118654752f)));
}

// ---------------- degree ----------------
__global__ void k_deg(const int* __restrict__ row, int* __restrict__ deg) {
  int t = blockIdx.x * 256 + threadIdx.x;
  if (t < N_EDGES) atomicAdd(&deg[row[t]], 1);
}

// ---------------- CSR build: scan (+dinv fused) + scatter ----------------
__global__ void k_scan1(const int* __restrict__ deg, int* __restrict__ startofs,
                        int* __restrict__ bsums, float* __restrict__ dinv) {
  __shared__ int sd[256];
  int t = threadIdx.x;
  int i = blockIdx.x * 256 + t;
  int v = (i < N_NODES) ? deg[i] : 0;
  if (i < N_NODES) dinv[i] = rsqrtf((float)(v + 1));  // +1 self-loop
  sd[t] = v;
  __syncthreads();
  for (int off = 1; off < 256; off <<= 1) {
    int u = (t >= off) ? sd[t - off] : 0;
    __syncthreads();
    sd[t] += u;
    __syncthreads();
  }
  if (i < N_NODES) startofs[i] = sd[t] - v;
  if (t == 255) bsums[blockIdx.x] = sd[255];
}

__global__ void k_scan2(int* __restrict__ bsums, int nb) {
  if (threadIdx.x == 0 && blockIdx.x == 0) {
    int run = 0;
    for (int b = 0; b < nb; b++) { int x = bsums[b]; bsums[b] = run; run += x; }
  }
}

__global__ void k_scan3(int* __restrict__ startofs, int* __restrict__ cursor,
                        const int* __restrict__ bsums) {
  int i = blockIdx.x * 256 + threadIdx.x;
  if (i < N_NODES) {
    int s0 = startofs[i] + bsums[blockIdx.x];
    startofs[i] = s0;
    cursor[i] = s0;
  }
}

__global__ void k_scatter(const int* __restrict__ row, const int* __restrict__ col,
                          const float* __restrict__ dinv, int* __restrict__ cursor,
                          int* __restrict__ csr_col, float* __restrict__ csr_w) {
  int t = blockIdx.x * 256 + threadIdx.x;
  if (t < N_EDGES) {
    int r = row[t], c = col[t];
    int p = atomicAdd(&cursor[r], 1);
    csr_col[p] = c;
    csr_w[p] = dinv[r] * dinv[c];
  }
}

// ---------------- B-matrix build: Bt[j][n][k] bf16 (transposed for MFMA B) ----
__global__ void k_buildB(const float* __restrict__ W, const float* __restrict__ means,
                         const float* __restrict__ logvars, unsigned short* __restrict__ Bt) {
  int idx = blockIdx.x * 256 + threadIdx.x;  // < 11*128*256
  int j = idx >> 15;
  int rem = idx & 32767;
  int n = rem >> 8;
  int kk = rem & 255;
  float wv = W[kk * OUT_F + n];
  float val;
  if (j == 0) val = wv;                                        // W
  else if (j <= 5) val = means[(j - 1) * IN_F + kk] * wv;      // means_k * W
  else val = expf(logvars[(j - 6) * IN_F + kk]) * wv * wv;     // var_k * W^2
  Bt[idx] = f2bf(val);
}

// ---- fused 3-way SpMM (A@x0 | A@m | A2@m) + GMM responsibilities -------------
// One wave per node. Gathers fp32 x; derives x0/mask on the fly; emits bf16 G.
__global__ void k_spmm(const float* __restrict__ x, const float* __restrict__ logp,
                       const float* __restrict__ means, const float* __restrict__ logvars,
                       const int* __restrict__ startofs, const int* __restrict__ deg,
                       const float* __restrict__ dinv, const int* __restrict__ csr_col,
                       const float* __restrict__ csr_w, unsigned short* __restrict__ G,
                       float* __restrict__ sArr, float* __restrict__ gamma) {
  __shared__ float s_mean[K_MIX * IN_F];
  __shared__ float s_rv[K_MIX * IN_F];
  int t = threadIdx.x;
  for (int j = t; j < K_MIX * IN_F; j += 256) {
    s_mean[j] = means[j];
    s_rv[j] = expf(-logvars[j]);  // 1/var
  }
  __syncthreads();
  int node = blockIdx.x * 4 + (t >> 6);
  if (node >= N_NODES) return;
  int lane = t & 63;
  float ax[4] = {0, 0, 0, 0}, am[4] = {0, 0, 0, 0}, am2[4] = {0, 0, 0, 0};
  float gsum[K_MIX] = {0, 0, 0, 0, 0};
  float di = dinv[node];
  float ws = di * di, ws2 = ws * ws;
  {  // self-loop + GMM distance
    float4 xv = *(const float4*)(x + (size_t)node * IN_F + 4 * lane);
    float xf[4] = {xv.x, xv.y, xv.z, xv.w};
#pragma unroll
    for (int j = 0; j < 4; j++) {
      bool nn = (xf[j] != xf[j]);
      float x0 = nn ? 0.f : xf[j];
      float mf = nn ? 1.f : 0.f;
      ax[j] += ws * x0;
      am[j] += ws * mf;
      am2[j] += ws2 * mf;
      if (!nn) {
        int fi = 4 * lane + j;
#pragma unroll
        for (int k = 0; k < K_MIX; k++) {
          float d = xf[j] - s_mean[k * IN_F + fi];
          gsum[k] += d * d * s_rv[k * IN_F + fi];
        }
      }
    }
  }
  float ssum = ws;
  int st = startofs[node], len = deg[node];
  int c_nxt = 0; float w_nxt = 0.f;
  if (len > 0) { c_nxt = csr_col[st]; w_nxt = csr_w[st]; }
  for (int e = 0; e < len; e++) {
    int c = c_nxt;
    float w = w_nxt;
    if (e + 1 < len) { c_nxt = csr_col[st + e + 1]; w_nxt = csr_w[st + e + 1]; }
    float w2 = w * w;
    float4 xv = *(const float4*)(x + (size_t)c * IN_F + 4 * lane);
    float xf[4] = {xv.x, xv.y, xv.z, xv.w};
#pragma unroll
    for (int j = 0; j < 4; j++) {
      bool nn = (xf[j] != xf[j]);
      float x0 = nn ? 0.f : xf[j];
      float mf = nn ? 1.f : 0.f;
      ax[j] += w * x0;
      am[j] += w * mf;
      am2[j] += w2 * mf;
    }
    ssum += w;
  }
  ushort4 o;
  o.x = f2bf(ax[0]); o.y = f2bf(ax[1]); o.z = f2bf(ax[2]); o.w = f2bf(ax[3]);
  *(ushort4*)(G + (size_t)node * 768 + 4 * lane) = o;
  o.x = f2bf(am[0]); o.y = f2bf(am[1]); o.z = f2bf(am[2]); o.w = f2bf(am[3]);
  *(ushort4*)(G + (size_t)node * 768 + 256 + 4 * lane) = o;
  o.x = f2bf(am2[0]); o.y = f2bf(am2[1]); o.z = f2bf(am2[2]); o.w = f2bf(am2[3]);
  *(ushort4*)(G + (size_t)node * 768 + 512 + 4 * lane) = o;
#pragma unroll
  for (int k = 0; k < K_MIX; k++)
    for (int off = 32; off; off >>= 1) gsum[k] += __shfl_xor(gsum[k], off, 64);
  if (lane == 0) {
    sArr[node] = ssum;
    float lg[K_MIX], mx = -1e30f;
#pragma unroll
    for (int k = 0; k < K_MIX; k++) {
      lg[k] = logp[k] - 0.5f * gsum[k];
      mx = fmaxf(mx, lg[k]);
    }
    float se = 0.f;
#pragma unroll
    for (int k = 0; k < K_MIX; k++) { lg[k] = expf(lg[k] - mx); se += lg[k]; }
    float inv = 1.f / se;
#pragma unroll
    for (int k = 0; k < K_MIX; k++) gamma[node * K_MIX + k] = lg[k] * inv;
  }
}

// ---- fused MFMA GEMM + epilogue: no T materialization ------------------------
// Block: 32 rows x 64 cols; wave w covers cols [cg*64+w*16, +16), 2 row-patches.
// All 11 jt accumulators live in registers; epilogue in-register.
__global__ __launch_bounds__(256) void k_gemmf(const unsigned short* __restrict__ G,
                                               const unsigned short* __restrict__ Bt,
                                               const float* __restrict__ gamma,
                                               const float* __restrict__ sArr,
                                               const float* __restrict__ bias,
                                               float* __restrict__ out) {
  int row0 = blockIdx.x * 32;
  int cg = blockIdx.y;
  int t = threadIdx.x, wave = t >> 6, lane = t & 63;
  int quad = lane >> 4, l16 = lane & 15;
  __shared__ float lgam[32][K_MIX];
  __shared__ float ls[32];
  if (t < 32) ls[t] = sArr[row0 + t];
  if (t < 32 * K_MIX) lgam[t / K_MIX][t % K_MIX] = gamma[(row0 + t / K_MIX) * K_MIX + t % K_MIX];
  __syncthreads();

  const unsigned short* Arow0 = G + (size_t)(row0 + l16) * 768;
  const unsigned short* Arow1 = G + (size_t)(row0 + 16 + l16) * 768;
  int colg = cg * 64 + wave * 16 + l16;      // global out col == tile-local col
  const unsigned short* Brow = Bt + (size_t)colg * 256;

  floatx4 acc[2][NT];
  floatx4 z = {0.f, 0.f, 0.f, 0.f};
#pragma unroll
  for (int mi = 0; mi < 2; mi++)
#pragma unroll
    for (int j = 0; j < NT; j++) acc[mi][j] = z;

  for (int k0 = 0; k0 < 256; k0 += 32) {
    int ko = k0 + quad * 8;
    short8 a00 = *(const short8*)(Arow0 + ko);
    short8 a01 = *(const short8*)(Arow0 + 256 + ko);
    short8 a02 = *(const short8*)(Arow0 + 512 + ko);
    short8 a10 = *(const short8*)(Arow1 + ko);
    short8 a11 = *(const short8*)(Arow1 + 256 + ko);
    short8 a12 = *(const short8*)(Arow1 + 512 + ko);
    short8 b[NT];
#pragma unroll
    for (int j = 0; j < NT; j++)
      b[j] = *(const short8*)(Brow + j * 32768 + ko);
    acc[0][0] = __builtin_amdgcn_mfma_f32_16x16x32_bf16(a00, b[0], acc[0][0], 0, 0, 0);
    acc[1][0] = __builtin_amdgcn_mfma_f32_16x16x32_bf16(a10, b[0], acc[1][0], 0, 0, 0);
#pragma unroll
    for (int k = 0; k < K_MIX; k++) {
      acc[0][1 + k] = __builtin_amdgcn_mfma_f32_16x16x32_bf16(a01, b[1 + k], acc[0][1 + k], 0, 0, 0);
      acc[1][1 + k] = __builtin_amdgcn_mfma_f32_16x16x32_bf16(a11, b[1 + k], acc[1][1 + k], 0, 0, 0);
    }
#pragma unroll
    for (int k = 0; k < K_MIX; k++) {
      acc[0][6 + k] = __builtin_amdgcn_mfma_f32_16x16x32_bf16(a02, b[6 + k], acc[0][6 + k], 0, 0, 0);
      acc[1][6 + k] = __builtin_amdgcn_mfma_f32_16x16x32_bf16(a12, b[6 + k], acc[1][6 + k], 0, 0, 0);
    }
  }

  float bc = bias[colg];
#pragma unroll
  for (int mi = 0; mi < 2; mi++) {
#pragma unroll
    for (int reg = 0; reg < 4; reg++) {
      int rl = mi * 16 + quad * 4 + reg;
      int node = row0 + rl;
      float sv = ls[rl];
      float a = 0.f;
#pragma unroll
      for (int k = 0; k < K_MIX; k++) {
        float mu = acc[mi][0][reg] + acc[mi][1 + k][reg] + bc * sv;
        a += lgam[rl][k] * exrelu(mu, acc[mi][6 + k][reg]);
      }
      out[(size_t)node * OUT_F + colg] = a;
    }
  }
}

extern "C" void kernel_launch(void* const* d_in, const int* in_sizes, int n_in,
                              void* d_out, int out_size, void* d_ws, size_t ws_size,
                              hipStream_t stream) {
  const float* x = (const float*)d_in[0];
  const int* ei = (const int*)d_in[1];
  const float* logp = (const float*)d_in[2];
  const float* means = (const float*)d_in[3];
  const float* lvar = (const float*)d_in[4];
  const float* W = (const float*)d_in[5];
  const float* bias = (const float*)d_in[6];
  float* out = (float*)d_out;
  const int* row = ei;
  const int* col = ei + N_EDGES;

  char* p = (char*)d_ws;
  auto alloc = [&](size_t bytes) -> char* {
    char* q = p;
    p += (bytes + 255) & ~((size_t)255);
    return q;
  };
  int* deg = (int*)alloc(N_NODES * 4);
  float* dinv = (float*)alloc(N_NODES * 4);
  int* startofs = (int*)alloc(N_NODES * 4);
  int* cursor = (int*)alloc(N_NODES * 4);
  int* bsums = (int*)alloc(128 * 4);
  int* csr_col = (int*)alloc((size_t)N_EDGES * 4);
  float* csr_w = (float*)alloc((size_t)N_EDGES * 4);
  float* gamma = (float*)alloc((size_t)N_NODES * K_MIX * 4);
  float* sArr = (float*)alloc(N_NODES * 4);
  unsigned short* Bt = (unsigned short*)alloc((size_t)NT * 128 * 256 * 2);
  unsigned short* G = (unsigned short*)alloc((size_t)N_NODES * 768 * 2);

  hipMemsetAsync(deg, 0, N_NODES * 4, stream);
  k_deg<<<(N_EDGES + 255) / 256, 256, 0, stream>>>(row, deg);
  k_scan1<<<79, 256, 0, stream>>>(deg, startofs, bsums, dinv);
  k_scan2<<<1, 1, 0, stream>>>(bsums, 79);
  k_scan3<<<79, 256, 0, stream>>>(startofs, cursor, bsums);
  k_scatter<<<(N_EDGES + 255) / 256, 256, 0, stream>>>(row, col, dinv, cursor, csr_col, csr_w);
  k_buildB<<<(NT * 128 * 256) / 256, 256, 0, stream>>>(W, means, lvar, Bt);
  k_spmm<<<N_NODES / 4, 256, 0, stream>>>(x, logp, means, lvar, startofs, deg, dinv,
                                          csr_col, csr_w, G, sArr, gamma);
  k_gemmf<<<dim3(N_NODES / 32, 2), 256, 0, stream>>>(G, Bt, gamma, sArr, bias, out);
}

// Round 6
// 259.061 us; speedup vs baseline: 1.1327x; 1.1327x over previous
//
#include <hip/hip_runtime.h>
#include <stdint.h>

#define N_NODES 20000
#define N_EDGES 320000
#define K_MIX 5
#define IN_F 256
#define OUT_F 128
#define NT 11              /* 1 + 2K column tiles of 128 */
#define TC (NT * OUT_F)    /* 1408 */

typedef __attribute__((ext_vector_type(8))) short short8;
typedef __attribute__((ext_vector_type(4))) float floatx4;

__device__ __forceinline__ float bf2f(unsigned int u) {
  union { unsigned int i; float f; } v;
  v.i = (u & 0xffffu) << 16;
  return v.f;
}
__device__ __forceinline__ unsigned short f2bf(float f) {
  union { float f; unsigned int i; } v;
  v.f = f;
  unsigned int x = v.i;
  unsigned int r = (x + 0x7fffu + ((x >> 16) & 1u)) >> 16;
  return (unsigned short)r;
}

__device__ __forceinline__ float exrelu(float mu, float sig) {
  // E[relu(X)], X ~ N(mu, sig) (sig is the variance). sig==0 -> relu(mu).
  if (sig < 1e-30f) return fmaxf(mu, 0.f);
  float ss = sqrtf(sig);
  float w = mu / ss;
  return ss * (expf(-0.5f * w * w) * 0.3989422804014327f +
               0.5f * w * (1.f + erff(w * 0.70710678118654752f)));
}

// ---------------- degree ----------------
__global__ void k_deg(const int* __restrict__ row, int* __restrict__ deg) {
  int t = blockIdx.x * 256 + threadIdx.x;
  if (t < N_EDGES) atomicAdd(&deg[row[t]], 1);
}

// ---------------- CSR build: scan (+dinv fused) + scatter ----------------
__global__ void k_scan1(const int* __restrict__ deg, int* __restrict__ startofs,
                        int* __restrict__ bsums, float* __restrict__ dinv) {
  __shared__ int sd[256];
  int t = threadIdx.x;
  int i = blockIdx.x * 256 + t;
  int v = (i < N_NODES) ? deg[i] : 0;
  if (i < N_NODES) dinv[i] = rsqrtf((float)(v + 1));  // +1 self-loop
  sd[t] = v;
  __syncthreads();
  for (int off = 1; off < 256; off <<= 1) {
    int u = (t >= off) ? sd[t - off] : 0;
    __syncthreads();
    sd[t] += u;
    __syncthreads();
  }
  if (i < N_NODES) startofs[i] = sd[t] - v;
  if (t == 255) bsums[blockIdx.x] = sd[255];
}

__global__ void k_scan2(int* __restrict__ bsums, int nb) {
  if (threadIdx.x == 0 && blockIdx.x == 0) {
    int run = 0;
    for (int b = 0; b < nb; b++) { int x = bsums[b]; bsums[b] = run; run += x; }
  }
}

__global__ void k_scan3(int* __restrict__ startofs, int* __restrict__ cursor,
                        const int* __restrict__ bsums) {
  int i = blockIdx.x * 256 + threadIdx.x;
  if (i < N_NODES) {
    int s0 = startofs[i] + bsums[blockIdx.x];
    startofs[i] = s0;
    cursor[i] = s0;
  }
}

__global__ void k_scatter(const int* __restrict__ row, const int* __restrict__ col,
                          const float* __restrict__ dinv, int* __restrict__ cursor,
                          int* __restrict__ csr_col, float* __restrict__ csr_w) {
  int t = blockIdx.x * 256 + threadIdx.x;
  if (t < N_EDGES) {
    int r = row[t], c = col[t];
    int p = atomicAdd(&cursor[r], 1);
    csr_col[p] = c;
    csr_w[p] = dinv[r] * dinv[c];
  }
}

// ---------------- B-matrix build: Bt[j][n][k] bf16 (transposed for MFMA B) ----
__global__ void k_buildB(const float* __restrict__ W, const float* __restrict__ means,
                         const float* __restrict__ logvars, unsigned short* __restrict__ Bt) {
  int idx = blockIdx.x * 256 + threadIdx.x;  // < 11*128*256
  int j = idx >> 15;
  int rem = idx & 32767;
  int n = rem >> 8;
  int kk = rem & 255;
  float wv = W[kk * OUT_F + n];
  float val;
  if (j == 0) val = wv;                                        // W
  else if (j <= 5) val = means[(j - 1) * IN_F + kk] * wv;      // means_k * W
  else val = expf(logvars[(j - 6) * IN_F + kk]) * wv * wv;     // var_k * W^2
  Bt[idx] = f2bf(val);
}

// ---- prep: pack x -> bf16 X0 + NaN bitmask, and GMM responsibilities ---------
// One wave per node, 4 nodes/block. Mask: Mb[node*4+j] bit l = isnan(x[4l+j]).
__global__ void k_prepx(const float* __restrict__ x, const float* __restrict__ logp,
                        const float* __restrict__ means, const float* __restrict__ logvars,
                        unsigned short* __restrict__ X0, unsigned long long* __restrict__ Mb,
                        float* __restrict__ gamma) {
  __shared__ float s_mean[K_MIX * IN_F];
  __shared__ float s_rv[K_MIX * IN_F];
  int t = threadIdx.x;
  for (int j = t; j < K_MIX * IN_F; j += 256) {
    s_mean[j] = means[j];
    s_rv[j] = expf(-logvars[j]);  // 1/var
  }
  __syncthreads();
  int node = blockIdx.x * 4 + (t >> 6);
  if (node >= N_NODES) return;
  int lane = t & 63;
  float4 xv = *(const float4*)(x + (size_t)node * IN_F + 4 * lane);
  float xf[4] = {xv.x, xv.y, xv.z, xv.w};
  float gsum[K_MIX] = {0, 0, 0, 0, 0};
  ushort4 o;
  unsigned short* op = (unsigned short*)&o;
#pragma unroll
  for (int j = 0; j < 4; j++) {
    bool nn = (xf[j] != xf[j]);
    op[j] = f2bf(nn ? 0.f : xf[j]);
    unsigned long long bj = __ballot(nn);
    if (lane == 0) Mb[(size_t)node * 4 + j] = bj;
    if (!nn) {
      int fi = 4 * lane + j;
#pragma unroll
      for (int k = 0; k < K_MIX; k++) {
        float d = xf[j] - s_mean[k * IN_F + fi];
        gsum[k] += d * d * s_rv[k * IN_F + fi];
      }
    }
  }
  *(ushort4*)(X0 + (size_t)node * IN_F + 4 * lane) = o;
#pragma unroll
  for (int k = 0; k < K_MIX; k++)
    for (int off = 32; off; off >>= 1) gsum[k] += __shfl_xor(gsum[k], off, 64);
  if (lane == 0) {
    float lg[K_MIX], mx = -1e30f;
#pragma unroll
    for (int k = 0; k < K_MIX; k++) {
      lg[k] = logp[k] - 0.5f * gsum[k];
      mx = fmaxf(mx, lg[k]);
    }
    float se = 0.f;
#pragma unroll
    for (int k = 0; k < K_MIX; k++) { lg[k] = expf(lg[k] - mx); se += lg[k]; }
    float inv = 1.f / se;
#pragma unroll
    for (int k = 0; k < K_MIX; k++) gamma[node * K_MIX + k] = lg[k] * inv;
  }
}

// ---- fused 3-way SpMM: A@x0 | A@m | A2@m  (one wave per node) ----------------
// Gathers packed bf16 X0 (512 B/row) + 32 B mask instead of 1 KB fp32 row.
__global__ void k_spmm(const unsigned short* __restrict__ X0,
                       const unsigned long long* __restrict__ Mb,
                       const int* __restrict__ startofs, const int* __restrict__ deg,
                       const float* __restrict__ dinv, const int* __restrict__ csr_col,
                       const float* __restrict__ csr_w, unsigned short* __restrict__ G,
                       float* __restrict__ sArr) {
  int t = threadIdx.x;
  int node = blockIdx.x * 4 + (t >> 6);
  if (node >= N_NODES) return;
  int lane = t & 63;
  float ax[4] = {0, 0, 0, 0}, am[4] = {0, 0, 0, 0}, am2[4] = {0, 0, 0, 0};
  float di = dinv[node];
  float ws = di * di, ws2 = ws * ws;
  float ssum = ws;
  int st = startofs[node], len = deg[node];
  // iteration -1 = self loop
  int c_nxt = node; float w_nxt = ws, w2s_nxt = ws2;
  for (int e = -1; e < len; e++) {
    int c = c_nxt;
    float w = w_nxt, wm2 = w2s_nxt;
    if (e + 1 < len) {
      c_nxt = csr_col[st + e + 1];
      w_nxt = csr_w[st + e + 1];
      w2s_nxt = w_nxt * w_nxt;
    }
    ushort4 xv = *(const ushort4*)(X0 + (size_t)c * IN_F + 4 * lane);
    unsigned long long m0 = Mb[(size_t)c * 4 + 0];
    unsigned long long m1 = Mb[(size_t)c * 4 + 1];
    unsigned long long m2 = Mb[(size_t)c * 4 + 2];
    unsigned long long m3 = Mb[(size_t)c * 4 + 3];
    float mf0 = (float)((m0 >> lane) & 1ull);
    float mf1 = (float)((m1 >> lane) & 1ull);
    float mf2 = (float)((m2 >> lane) & 1ull);
    float mf3 = (float)((m3 >> lane) & 1ull);
    ax[0] += w * bf2f(xv.x); ax[1] += w * bf2f(xv.y);
    ax[2] += w * bf2f(xv.z); ax[3] += w * bf2f(xv.w);
    am[0] += w * mf0; am[1] += w * mf1; am[2] += w * mf2; am[3] += w * mf3;
    am2[0] += wm2 * mf0; am2[1] += wm2 * mf1; am2[2] += wm2 * mf2; am2[3] += wm2 * mf3;
    if (e >= 0) ssum += w;
  }
  ushort4 o;
  o.x = f2bf(ax[0]); o.y = f2bf(ax[1]); o.z = f2bf(ax[2]); o.w = f2bf(ax[3]);
  *(ushort4*)(G + (size_t)node * 768 + 4 * lane) = o;
  o.x = f2bf(am[0]); o.y = f2bf(am[1]); o.z = f2bf(am[2]); o.w = f2bf(am[3]);
  *(ushort4*)(G + (size_t)node * 768 + 256 + 4 * lane) = o;
  o.x = f2bf(am2[0]); o.y = f2bf(am2[1]); o.z = f2bf(am2[2]); o.w = f2bf(am2[3]);
  *(ushort4*)(G + (size_t)node * 768 + 512 + 4 * lane) = o;
  if (lane == 0) sArr[node] = ssum;
}

// ---- MFMA GEMM, LDS-staged (m97-style): T = (G slice) @ B_jt, bf16 out -------
// 128x128 tile, BK=64, XOR-swizzled LDS chunks (16 B units) for conflict-free
// ds_read_b128 / ds_write_b128.
__global__ __launch_bounds__(256) void k_gemm(const unsigned short* __restrict__ G,
                                              const unsigned short* __restrict__ Bt,
                                              unsigned short* __restrict__ T) {
  __shared__ char Als[128 * 64 * 2];  // 16 KB
  __shared__ char Bls[128 * 64 * 2];  // 16 KB
  int mt = blockIdx.x, jt = blockIdx.y;
  int aoff = (jt == 0) ? 0 : (jt <= 5 ? 256 : 512);
  int t = threadIdx.x, wave = t >> 6, lane = t & 63;
  int wr = wave >> 1, wc = wave & 1;
  int quad = lane >> 4, l16 = lane & 15;
  const unsigned short* Bp = Bt + (size_t)jt * 32768;

  floatx4 acc[4][4];
  floatx4 z = {0.f, 0.f, 0.f, 0.f};
#pragma unroll
  for (int mi = 0; mi < 4; mi++)
#pragma unroll
    for (int ni = 0; ni < 4; ni++) acc[mi][ni] = z;

  for (int k0 = 0; k0 < 256; k0 += 64) {
    __syncthreads();
    // stage A(128x64) and B(128x64): 1024 chunks of 16 B each
#pragma unroll
    for (int i = 0; i < 4; i++) {
      int f = i * 256 + t;
      int r = f >> 3, cchunk = f & 7;
      int sw = cchunk ^ (r & 7);
      int gr = mt * 128 + r;
      if (gr >= N_NODES) gr = N_NODES - 1;
      *(uint4*)(Als + r * 128 + sw * 16) =
          *(const uint4*)(G + (size_t)gr * 768 + aoff + k0 + cchunk * 8);
      *(uint4*)(Bls + r * 128 + sw * 16) =
          *(const uint4*)(Bp + (size_t)r * 256 + k0 + cchunk * 8);
    }
    __syncthreads();
#pragma unroll
    for (int ks = 0; ks < 2; ks++) {
      int cc = ks * 4 + quad;
      short8 a[4], b[4];
#pragma unroll
      for (int mi = 0; mi < 4; mi++) {
        int r = wr * 64 + mi * 16 + l16;
        a[mi] = *(const short8*)(Als + r * 128 + (cc ^ (r & 7)) * 16);
      }
#pragma unroll
      for (int ni = 0; ni < 4; ni++) {
        int r = wc * 64 + ni * 16 + l16;
        b[ni] = *(const short8*)(Bls + r * 128 + (cc ^ (r & 7)) * 16);
      }
#pragma unroll
      for (int mi = 0; mi < 4; mi++)
#pragma unroll
        for (int ni = 0; ni < 4; ni++)
          acc[mi][ni] = __builtin_amdgcn_mfma_f32_16x16x32_bf16(a[mi], b[ni], acc[mi][ni], 0, 0, 0);
    }
  }
#pragma unroll
  for (int mi = 0; mi < 4; mi++)
#pragma unroll
    for (int ni = 0; ni < 4; ni++) {
      int gc = jt * 128 + wc * 64 + ni * 16 + l16;
#pragma unroll
      for (int reg = 0; reg < 4; reg++) {
        int gr = mt * 128 + wr * 64 + mi * 16 + quad * 4 + reg;
        if (gr < N_NODES) T[(size_t)gr * TC + gc] = f2bf(acc[mi][ni][reg]);
      }
    }
}

// ---------------- epilogue: Ex_relu + gamma-weighted combine ----------------
__global__ void k_final(const unsigned short* __restrict__ T, const float* __restrict__ gamma,
                        const float* __restrict__ sArr, const float* __restrict__ bias,
                        float* __restrict__ out) {
  int t = threadIdx.x;
  int node = blockIdx.x * 4 + (t >> 6);
  if (node >= N_NODES) return;
  int lane = t & 63;
  int o0 = 2 * lane;
  float g[K_MIX];
#pragma unroll
  for (int k = 0; k < K_MIX; k++) g[k] = gamma[node * K_MIX + k];
  float sv = sArr[node];
  float b0 = bias[o0], b1 = bias[o0 + 1];
  const unsigned short* Tr = T + (size_t)node * TC;
  unsigned int c0u = *(const unsigned int*)(Tr + o0);
  float cx0 = bf2f(c0u), cx1 = bf2f(c0u >> 16);
  float a0 = 0.f, a1 = 0.f;
#pragma unroll
  for (int k = 0; k < K_MIX; k++) {
    unsigned int tm = *(const unsigned int*)(Tr + 128 * (1 + k) + o0);
    unsigned int tv = *(const unsigned int*)(Tr + 128 * (6 + k) + o0);
    float mu0 = cx0 + bf2f(tm) + b0 * sv;
    float mu1 = cx1 + bf2f(tm >> 16) + b1 * sv;
    a0 += g[k] * exrelu(mu0, bf2f(tv));
    a1 += g[k] * exrelu(mu1, bf2f(tv >> 16));
  }
  float2 ov = {a0, a1};
  *(float2*)(out + (size_t)node * OUT_F + o0) = ov;
}

extern "C" void kernel_launch(void* const* d_in, const int* in_sizes, int n_in,
                              void* d_out, int out_size, void* d_ws, size_t ws_size,
                              hipStream_t stream) {
  const float* x = (const float*)d_in[0];
  const int* ei = (const int*)d_in[1];
  const float* logp = (const float*)d_in[2];
  const float* means = (const float*)d_in[3];
  const float* lvar = (const float*)d_in[4];
  const float* W = (const float*)d_in[5];
  const float* bias = (const float*)d_in[6];
  float* out = (float*)d_out;
  const int* row = ei;
  const int* col = ei + N_EDGES;

  char* p = (char*)d_ws;
  auto alloc = [&](size_t bytes) -> char* {
    char* q = p;
    p += (bytes + 255) & ~((size_t)255);
    return q;
  };
  // total ~100 MB (ws is 256 MiB)
  int* deg = (int*)alloc(N_NODES * 4);
  float* dinv = (float*)alloc(N_NODES * 4);
  int* startofs = (int*)alloc(N_NODES * 4);
  int* cursor = (int*)alloc(N_NODES * 4);
  int* bsums = (int*)alloc(128 * 4);
  int* csr_col = (int*)alloc((size_t)N_EDGES * 4);
  float* csr_w = (float*)alloc((size_t)N_EDGES * 4);
  float* gamma = (float*)alloc((size_t)N_NODES * K_MIX * 4);
  float* sArr = (float*)alloc(N_NODES * 4);
  unsigned short* Bt = (unsigned short*)alloc((size_t)NT * 128 * 256 * 2);
  unsigned short* X0 = (unsigned short*)alloc((size_t)N_NODES * IN_F * 2);
  unsigned long long* Mb = (unsigned long long*)alloc((size_t)N_NODES * 4 * 8);
  unsigned short* G = (unsigned short*)alloc((size_t)N_NODES * 768 * 2);
  unsigned short* T = (unsigned short*)alloc((size_t)N_NODES * TC * 2);

  hipMemsetAsync(deg, 0, N_NODES * 4, stream);
  k_deg<<<(N_EDGES + 255) / 256, 256, 0, stream>>>(row, deg);
  k_scan1<<<79, 256, 0, stream>>>(deg, startofs, bsums, dinv);
  k_scan2<<<1, 1, 0, stream>>>(bsums, 79);
  k_scan3<<<79, 256, 0, stream>>>(startofs, cursor, bsums);
  k_scatter<<<(N_EDGES + 255) / 256, 256, 0, stream>>>(row, col, dinv, cursor, csr_col, csr_w);
  k_buildB<<<(NT * 128 * 256) / 256, 256, 0, stream>>>(W, means, lvar, Bt);
  k_prepx<<<N_NODES / 4, 256, 0, stream>>>(x, logp, means, lvar, X0, Mb, gamma);
  k_spmm<<<N_NODES / 4, 256, 0, stream>>>(X0, Mb, startofs, deg, dinv, csr_col, csr_w, G, sArr);
  k_gemm<<<dim3((N_NODES + 127) / 128, NT), 256, 0, stream>>>(G, Bt, T);
  k_final<<<N_NODES / 4, 256, 0, stream>>>(T, gamma, sArr, bias, out);
}

// Round 7
// 254.402 us; speedup vs baseline: 1.1534x; 1.0183x over previous
//
#include <hip/hip_runtime.h>
#include <stdint.h>

#define N_NODES 20000
#define N_EDGES 320000
#define K_MIX 5
#define IN_F 256
#define OUT_F 128
#define NT 11              /* 1 + 2K column tiles of 128 */
#define TC (NT * OUT_F)    /* 1408 */

typedef __attribute__((ext_vector_type(8))) short short8;
typedef __attribute__((ext_vector_type(4))) float floatx4;

__device__ __forceinline__ float bf2f(unsigned int u) {
  union { unsigned int i; float f; } v;
  v.i = (u & 0xffffu) << 16;
  return v.f;
}
__device__ __forceinline__ unsigned short f2bf(float f) {
  union { float f; unsigned int i; } v;
  v.f = f;
  unsigned int x = v.i;
  unsigned int r = (x + 0x7fffu + ((x >> 16) & 1u)) >> 16;
  return (unsigned short)r;
}

__device__ __forceinline__ float exrelu(float mu, float sig) {
  // E[relu(X)], X ~ N(mu, sig) (sig is the variance). sig==0 -> relu(mu).
  if (sig < 1e-30f) return fmaxf(mu, 0.f);
  float ss = sqrtf(sig);
  float w = mu / ss;
  return ss * (expf(-0.5f * w * w) * 0.3989422804014327f +
               0.5f * w * (1.f + erff(w * 0.70710678118654752f)));
}

// ---------------- degree ----------------
__global__ void k_deg(const int* __restrict__ row, int* __restrict__ deg) {
  int t = blockIdx.x * 256 + threadIdx.x;
  if (t < N_EDGES) atomicAdd(&deg[row[t]], 1);
}

// ---------------- CSR build: scan (+dinv fused) + scatter ----------------
__global__ void k_scan1(const int* __restrict__ deg, int* __restrict__ startofs,
                        int* __restrict__ bsums, float* __restrict__ dinv) {
  __shared__ int sd[256];
  int t = threadIdx.x;
  int i = blockIdx.x * 256 + t;
  int v = (i < N_NODES) ? deg[i] : 0;
  if (i < N_NODES) dinv[i] = rsqrtf((float)(v + 1));  // +1 self-loop
  sd[t] = v;
  __syncthreads();
  for (int off = 1; off < 256; off <<= 1) {
    int u = (t >= off) ? sd[t - off] : 0;
    __syncthreads();
    sd[t] += u;
    __syncthreads();
  }
  if (i < N_NODES) startofs[i] = sd[t] - v;
  if (t == 255) bsums[blockIdx.x] = sd[255];
}

__global__ void k_scan2(int* __restrict__ bsums, int nb) {
  if (threadIdx.x == 0 && blockIdx.x == 0) {
    int run = 0;
    for (int b = 0; b < nb; b++) { int x = bsums[b]; bsums[b] = run; run += x; }
  }
}

__global__ void k_scan3(int* __restrict__ startofs, int* __restrict__ cursor,
                        const int* __restrict__ bsums) {
  int i = blockIdx.x * 256 + threadIdx.x;
  if (i < N_NODES) {
    int s0 = startofs[i] + bsums[blockIdx.x];
    startofs[i] = s0;
    cursor[i] = s0;
  }
}

__global__ void k_scatter(const int* __restrict__ row, const int* __restrict__ col,
                          const float* __restrict__ dinv, int* __restrict__ cursor,
                          int* __restrict__ csr_col, float* __restrict__ csr_w) {
  int t = blockIdx.x * 256 + threadIdx.x;
  if (t < N_EDGES) {
    int r = row[t], c = col[t];
    int p = atomicAdd(&cursor[r], 1);
    csr_col[p] = c;
    csr_w[p] = dinv[r] * dinv[c];
  }
}

// ---------------- B-matrix build: Bt[j][n][k] bf16 (transposed for MFMA B) ----
__global__ void k_buildB(const float* __restrict__ W, const float* __restrict__ means,
                         const float* __restrict__ logvars, unsigned short* __restrict__ Bt) {
  int idx = blockIdx.x * 256 + threadIdx.x;  // < 11*128*256
  int j = idx >> 15;
  int rem = idx & 32767;
  int n = rem >> 8;
  int kk = rem & 255;
  float wv = W[kk * OUT_F + n];
  float val;
  if (j == 0) val = wv;                                        // W
  else if (j <= 5) val = means[(j - 1) * IN_F + kk] * wv;      // means_k * W
  else val = expf(logvars[(j - 6) * IN_F + kk]) * wv * wv;     // var_k * W^2
  Bt[idx] = f2bf(val);
}

// ---- prep: pack x -> bf16 X0 (NaN marker 0x7FC0 for missing) + gamma ---------
__global__ void k_prepx(const float* __restrict__ x, const float* __restrict__ logp,
                        const float* __restrict__ means, const float* __restrict__ logvars,
                        unsigned short* __restrict__ X0, float* __restrict__ gamma) {
  __shared__ float s_mean[K_MIX * IN_F];
  __shared__ float s_rv[K_MIX * IN_F];
  int t = threadIdx.x;
  for (int j = t; j < K_MIX * IN_F; j += 256) {
    s_mean[j] = means[j];
    s_rv[j] = expf(-logvars[j]);  // 1/var
  }
  __syncthreads();
  int node = blockIdx.x * 4 + (t >> 6);
  if (node >= N_NODES) return;
  int lane = t & 63;
  float4 xv = *(const float4*)(x + (size_t)node * IN_F + 4 * lane);
  float xf[4] = {xv.x, xv.y, xv.z, xv.w};
  float gsum[K_MIX] = {0, 0, 0, 0, 0};
  ushort4 o;
  unsigned short* op = (unsigned short*)&o;
#pragma unroll
  for (int j = 0; j < 4; j++) {
    bool nn = (xf[j] != xf[j]);
    op[j] = nn ? (unsigned short)0x7FC0 : f2bf(xf[j]);
    if (!nn) {
      int fi = 4 * lane + j;
#pragma unroll
      for (int k = 0; k < K_MIX; k++) {
        float d = xf[j] - s_mean[k * IN_F + fi];
        gsum[k] += d * d * s_rv[k * IN_F + fi];
      }
    }
  }
  *(ushort4*)(X0 + node * IN_F + 4 * lane) = o;
#pragma unroll
  for (int k = 0; k < K_MIX; k++)
    for (int off = 32; off; off >>= 1) gsum[k] += __shfl_xor(gsum[k], off, 64);
  if (lane == 0) {
    float lg[K_MIX], mx = -1e30f;
#pragma unroll
    for (int k = 0; k < K_MIX; k++) {
      lg[k] = logp[k] - 0.5f * gsum[k];
      mx = fmaxf(mx, lg[k]);
    }
    float se = 0.f;
#pragma unroll
    for (int k = 0; k < K_MIX; k++) { lg[k] = expf(lg[k] - mx); se += lg[k]; }
    float inv = 1.f / se;
#pragma unroll
    for (int k = 0; k < K_MIX; k++) gamma[node * K_MIX + k] = lg[k] * inv;
  }
}

// ---- fused 3-way SpMM: A@x0 | A@m | A2@m  (one wave per node) ----------------
// Single 512 B NaN-encoded row gather per edge; software-pipelined prefetch.
__global__ void k_spmm(const unsigned short* __restrict__ X0,
                       const int* __restrict__ startofs, const int* __restrict__ deg,
                       const float* __restrict__ dinv, const int* __restrict__ csr_col,
                       const float* __restrict__ csr_w, unsigned short* __restrict__ G,
                       float* __restrict__ sArr) {
  int t = threadIdx.x;
  int node = blockIdx.x * 4 + (t >> 6);
  if (node >= N_NODES) return;
  int lane = t & 63;
  float ax[4] = {0, 0, 0, 0}, am[4] = {0, 0, 0, 0}, am2[4] = {0, 0, 0, 0};
  float di = dinv[node];
  float ws = di * di;
  float ssum = ws;
  int st = startofs[node], len = deg[node];
  // stage: current edge data (starts with the self-loop)
  ushort4 xv_c = *(const ushort4*)(X0 + node * IN_F + 4 * lane);
  float w_c = ws, w2_c = ws * ws;
  ushort4 xv_n;
  float w_n = 0.f, w2_n = 0.f;
  for (int e = 0;; e++) {
    bool have_next = (e < len);
    if (have_next) {  // issue prefetch for edge e
      int cn = csr_col[st + e];
      w_n = csr_w[st + e];
      xv_n = *(const ushort4*)(X0 + cn * IN_F + 4 * lane);
      w2_n = w_n * w_n;
      ssum += w_n;
    }
    // consume current stage
    const unsigned short* xp = (const unsigned short*)&xv_c;
#pragma unroll
    for (int j = 0; j < 4; j++) {
      float xf = bf2f(xp[j]);
      bool nn = (xf != xf);
      float x0 = nn ? 0.f : xf;
      ax[j] = fmaf(w_c, x0, ax[j]);
      am[j] += nn ? w_c : 0.f;
      am2[j] += nn ? w2_c : 0.f;
    }
    if (!have_next) break;
    xv_c = xv_n; w_c = w_n; w2_c = w2_n;
  }
  ushort4 o;
  o.x = f2bf(ax[0]); o.y = f2bf(ax[1]); o.z = f2bf(ax[2]); o.w = f2bf(ax[3]);
  *(ushort4*)(G + node * 768 + 4 * lane) = o;
  o.x = f2bf(am[0]); o.y = f2bf(am[1]); o.z = f2bf(am[2]); o.w = f2bf(am[3]);
  *(ushort4*)(G + node * 768 + 256 + 4 * lane) = o;
  o.x = f2bf(am2[0]); o.y = f2bf(am2[1]); o.z = f2bf(am2[2]); o.w = f2bf(am2[3]);
  *(ushort4*)(G + node * 768 + 512 + 4 * lane) = o;
  if (lane == 0) sArr[node] = ssum;
}

// ---- MFMA GEMM, LDS-staged (m97-style): T = (G slice) @ B_jt, bf16 out -------
__global__ __launch_bounds__(256) void k_gemm(const unsigned short* __restrict__ G,
                                              const unsigned short* __restrict__ Bt,
                                              unsigned short* __restrict__ T) {
  __shared__ char Als[128 * 64 * 2];  // 16 KB
  __shared__ char Bls[128 * 64 * 2];  // 16 KB
  int mt = blockIdx.x, jt = blockIdx.y;
  int aoff = (jt == 0) ? 0 : (jt <= 5 ? 256 : 512);
  int t = threadIdx.x, wave = t >> 6, lane = t & 63;
  int wr = wave >> 1, wc = wave & 1;
  int quad = lane >> 4, l16 = lane & 15;
  const unsigned short* Bp = Bt + (size_t)jt * 32768;

  floatx4 acc[4][4];
  floatx4 z = {0.f, 0.f, 0.f, 0.f};
#pragma unroll
  for (int mi = 0; mi < 4; mi++)
#pragma unroll
    for (int ni = 0; ni < 4; ni++) acc[mi][ni] = z;

  for (int k0 = 0; k0 < 256; k0 += 64) {
    __syncthreads();
#pragma unroll
    for (int i = 0; i < 4; i++) {
      int f = i * 256 + t;
      int r = f >> 3, cchunk = f & 7;
      int sw = cchunk ^ (r & 7);
      int gr = mt * 128 + r;
      if (gr >= N_NODES) gr = N_NODES - 1;
      *(uint4*)(Als + r * 128 + sw * 16) =
          *(const uint4*)(G + (size_t)gr * 768 + aoff + k0 + cchunk * 8);
      *(uint4*)(Bls + r * 128 + sw * 16) =
          *(const uint4*)(Bp + (size_t)r * 256 + k0 + cchunk * 8);
    }
    __syncthreads();
#pragma unroll
    for (int ks = 0; ks < 2; ks++) {
      int cc = ks * 4 + quad;
      short8 a[4], b[4];
#pragma unroll
      for (int mi = 0; mi < 4; mi++) {
        int r = wr * 64 + mi * 16 + l16;
        a[mi] = *(const short8*)(Als + r * 128 + (cc ^ (r & 7)) * 16);
      }
#pragma unroll
      for (int ni = 0; ni < 4; ni++) {
        int r = wc * 64 + ni * 16 + l16;
        b[ni] = *(const short8*)(Bls + r * 128 + (cc ^ (r & 7)) * 16);
      }
#pragma unroll
      for (int mi = 0; mi < 4; mi++)
#pragma unroll
        for (int ni = 0; ni < 4; ni++)
          acc[mi][ni] = __builtin_amdgcn_mfma_f32_16x16x32_bf16(a[mi], b[ni], acc[mi][ni], 0, 0, 0);
    }
  }
#pragma unroll
  for (int mi = 0; mi < 4; mi++)
#pragma unroll
    for (int ni = 0; ni < 4; ni++) {
      int gc = jt * 128 + wc * 64 + ni * 16 + l16;
#pragma unroll
      for (int reg = 0; reg < 4; reg++) {
        int gr = mt * 128 + wr * 64 + mi * 16 + quad * 4 + reg;
        if (gr < N_NODES) T[(size_t)gr * TC + gc] = f2bf(acc[mi][ni][reg]);
      }
    }
}

// ---------------- epilogue: Ex_relu + gamma-weighted combine ----------------
__global__ void k_final(const unsigned short* __restrict__ T, const float* __restrict__ gamma,
                        const float* __restrict__ sArr, const float* __restrict__ bias,
                        float* __restrict__ out) {
  int t = threadIdx.x;
  int node = blockIdx.x * 4 + (t >> 6);
  if (node >= N_NODES) return;
  int lane = t & 63;
  int o0 = 2 * lane;
  float g[K_MIX];
#pragma unroll
  for (int k = 0; k < K_MIX; k++) g[k] = gamma[node * K_MIX + k];
  float sv = sArr[node];
  float b0 = bias[o0], b1 = bias[o0 + 1];
  const unsigned short* Tr = T + (size_t)node * TC;
  unsigned int c0u = *(const unsigned int*)(Tr + o0);
  float cx0 = bf2f(c0u), cx1 = bf2f(c0u >> 16);
  float a0 = 0.f, a1 = 0.f;
#pragma unroll
  for (int k = 0; k < K_MIX; k++) {
    unsigned int tm = *(const unsigned int*)(Tr + 128 * (1 + k) + o0);
    unsigned int tv = *(const unsigned int*)(Tr + 128 * (6 + k) + o0);
    float mu0 = cx0 + bf2f(tm) + b0 * sv;
    float mu1 = cx1 + bf2f(tm >> 16) + b1 * sv;
    a0 += g[k] * exrelu(mu0, bf2f(tv));
    a1 += g[k] * exrelu(mu1, bf2f(tv >> 16));
  }
  float2 ov = {a0, a1};
  *(float2*)(out + (size_t)node * OUT_F + o0) = ov;
}

extern "C" void kernel_launch(void* const* d_in, const int* in_sizes, int n_in,
                              void* d_out, int out_size, void* d_ws, size_t ws_size,
                              hipStream_t stream) {
  const float* x = (const float*)d_in[0];
  const int* ei = (const int*)d_in[1];
  const float* logp = (const float*)d_in[2];
  const float* means = (const float*)d_in[3];
  const float* lvar = (const float*)d_in[4];
  const float* W = (const float*)d_in[5];
  const float* bias = (const float*)d_in[6];
  float* out = (float*)d_out;
  const int* row = ei;
  const int* col = ei + N_EDGES;

  char* p = (char*)d_ws;
  auto alloc = [&](size_t bytes) -> char* {
    char* q = p;
    p += (bytes + 255) & ~((size_t)255);
    return q;
  };
  int* deg = (int*)alloc(N_NODES * 4);
  float* dinv = (float*)alloc(N_NODES * 4);
  int* startofs = (int*)alloc(N_NODES * 4);
  int* cursor = (int*)alloc(N_NODES * 4);
  int* bsums = (int*)alloc(128 * 4);
  int* csr_col = (int*)alloc((size_t)N_EDGES * 4);
  float* csr_w = (float*)alloc((size_t)N_EDGES * 4);
  float* gamma = (float*)alloc((size_t)N_NODES * K_MIX * 4);
  float* sArr = (float*)alloc(N_NODES * 4);
  unsigned short* Bt = (unsigned short*)alloc((size_t)NT * 128 * 256 * 2);
  unsigned short* X0 = (unsigned short*)alloc((size_t)N_NODES * IN_F * 2);
  unsigned short* G = (unsigned short*)alloc((size_t)N_NODES * 768 * 2);
  unsigned short* T = (unsigned short*)alloc((size_t)N_NODES * TC * 2);

  hipMemsetAsync(deg, 0, N_NODES * 4, stream);
  k_deg<<<(N_EDGES + 255) / 256, 256, 0, stream>>>(row, deg);
  k_scan1<<<79, 256, 0, stream>>>(deg, startofs, bsums, dinv);
  k_scan2<<<1, 1, 0, stream>>>(bsums, 79);
  k_scan3<<<79, 256, 0, stream>>>(startofs, cursor, bsums);
  k_scatter<<<(N_EDGES + 255) / 256, 256, 0, stream>>>(row, col, dinv, cursor, csr_col, csr_w);
  k_buildB<<<(NT * 128 * 256) / 256, 256, 0, stream>>>(W, means, lvar, Bt);
  k_prepx<<<N_NODES / 4, 256, 0, stream>>>(x, logp, means, lvar, X0, gamma);
  k_spmm<<<N_NODES / 4, 256, 0, stream>>>(X0, startofs, deg, dinv, csr_col, csr_w, G, sArr);
  k_gemm<<<dim3((N_NODES + 127) / 128, NT), 256, 0, stream>>>(G, Bt, T);
  k_final<<<N_NODES / 4, 256, 0, stream>>>(T, gamma, sArr, bias, out);
}

// Round 8
// 236.787 us; speedup vs baseline: 1.2392x; 1.0744x over previous
//
#include <hip/hip_runtime.h>
#include <stdint.h>

#define N_NODES 20000
#define N_EDGES 320000
#define K_MIX 5
#define IN_F 256
#define OUT_F 128
#define NT 11              /* 1 + 2K column tiles of 128 */
#define TC (NT * OUT_F)    /* 1408 */

typedef __attribute__((ext_vector_type(8))) short short8;
typedef __attribute__((ext_vector_type(4))) float floatx4;

__device__ __forceinline__ float bf2f(unsigned int u) {
  union { unsigned int i; float f; } v;
  v.i = (u & 0xffffu) << 16;
  return v.f;
}
__device__ __forceinline__ unsigned short f2bf(float f) {
  union { float f; unsigned int i; } v;
  v.f = f;
  unsigned int x = v.i;
  unsigned int r = (x + 0x7fffu + ((x >> 16) & 1u)) >> 16;
  return (unsigned short)r;
}

__device__ __forceinline__ float exrelu(float mu, float sig) {
  // E[relu(X)], X ~ N(mu, sig) (sig is the variance). sig==0 -> relu(mu).
  if (sig < 1e-30f) return fmaxf(mu, 0.f);
  float ss = sqrtf(sig);
  float w = mu / ss;
  return ss * (expf(-0.5f * w * w) * 0.3989422804014327f +
               0.5f * w * (1.f + erff(w * 0.70710678118654752f)));
}

// ---------------- degree ----------------
__global__ void k_deg(const int* __restrict__ row, int* __restrict__ deg) {
  int t = blockIdx.x * 256 + threadIdx.x;
  if (t < N_EDGES) atomicAdd(&deg[row[t]], 1);
}

// ---------------- CSR build: scan (+dinv fused) + scatter ----------------
__global__ void k_scan1(const int* __restrict__ deg, int* __restrict__ startofs,
                        int* __restrict__ bsums, float* __restrict__ dinv) {
  __shared__ int sd[256];
  int t = threadIdx.x;
  int i = blockIdx.x * 256 + t;
  int v = (i < N_NODES) ? deg[i] : 0;
  if (i < N_NODES) dinv[i] = rsqrtf((float)(v + 1));  // +1 self-loop
  sd[t] = v;
  __syncthreads();
  for (int off = 1; off < 256; off <<= 1) {
    int u = (t >= off) ? sd[t - off] : 0;
    __syncthreads();
    sd[t] += u;
    __syncthreads();
  }
  if (i < N_NODES) startofs[i] = sd[t] - v;
  if (t == 255) bsums[blockIdx.x] = sd[255];
}

// parallel exclusive scan over <=128 block sums (single block of 128)
__global__ void k_scan2(int* __restrict__ bsums, int nb) {
  __shared__ int sd[128];
  int t = threadIdx.x;
  int v = (t < nb) ? bsums[t] : 0;
  sd[t] = v;
  __syncthreads();
  for (int off = 1; off < 128; off <<= 1) {
    int u = (t >= off) ? sd[t - off] : 0;
    __syncthreads();
    sd[t] += u;
    __syncthreads();
  }
  if (t < nb) bsums[t] = sd[t] - v;  // exclusive
}

__global__ void k_scan3(int* __restrict__ startofs, int* __restrict__ cursor,
                        const int* __restrict__ bsums) {
  int i = blockIdx.x * 256 + threadIdx.x;
  if (i < N_NODES) {
    int s0 = startofs[i] + bsums[blockIdx.x];
    startofs[i] = s0;
    cursor[i] = s0;
  }
}

__global__ void k_scatter(const int* __restrict__ row, const int* __restrict__ col,
                          const float* __restrict__ dinv, int* __restrict__ cursor,
                          int* __restrict__ csr_col, float* __restrict__ csr_w) {
  int t = blockIdx.x * 256 + threadIdx.x;
  if (t < N_EDGES) {
    int r = row[t], c = col[t];
    int p = atomicAdd(&cursor[r], 1);
    csr_col[p] = c;
    csr_w[p] = dinv[r] * dinv[c];
  }
}

// ---------------- B-matrix build: Bt[j][n][k] bf16 (transposed for MFMA B) ----
__global__ void k_buildB(const float* __restrict__ W, const float* __restrict__ means,
                         const float* __restrict__ logvars, unsigned short* __restrict__ Bt) {
  int idx = blockIdx.x * 256 + threadIdx.x;  // < 11*128*256
  int j = idx >> 15;
  int rem = idx & 32767;
  int n = rem >> 8;
  int kk = rem & 255;
  float wv = W[kk * OUT_F + n];
  float val;
  if (j == 0) val = wv;                                        // W
  else if (j <= 5) val = means[(j - 1) * IN_F + kk] * wv;      // means_k * W
  else val = expf(logvars[(j - 6) * IN_F + kk]) * wv * wv;     // var_k * W^2
  Bt[idx] = f2bf(val);
}

// ---- prep: pack x -> bf16 X0 (NaN marker 0x7FC0 for missing) + gamma ---------
__global__ void k_prepx(const float* __restrict__ x, const float* __restrict__ logp,
                        const float* __restrict__ means, const float* __restrict__ logvars,
                        unsigned short* __restrict__ X0, float* __restrict__ gamma) {
  __shared__ float s_mean[K_MIX * IN_F];
  __shared__ float s_rv[K_MIX * IN_F];
  int t = threadIdx.x;
  for (int j = t; j < K_MIX * IN_F; j += 256) {
    s_mean[j] = means[j];
    s_rv[j] = expf(-logvars[j]);  // 1/var
  }
  __syncthreads();
  int node = blockIdx.x * 4 + (t >> 6);
  if (node >= N_NODES) return;
  int lane = t & 63;
  float4 xv = *(const float4*)(x + (size_t)node * IN_F + 4 * lane);
  float xf[4] = {xv.x, xv.y, xv.z, xv.w};
  float gsum[K_MIX] = {0, 0, 0, 0, 0};
  ushort4 o;
  unsigned short* op = (unsigned short*)&o;
#pragma unroll
  for (int j = 0; j < 4; j++) {
    bool nn = (xf[j] != xf[j]);
    op[j] = nn ? (unsigned short)0x7FC0 : f2bf(xf[j]);
    if (!nn) {
      int fi = 4 * lane + j;
#pragma unroll
      for (int k = 0; k < K_MIX; k++) {
        float d = xf[j] - s_mean[k * IN_F + fi];
        gsum[k] += d * d * s_rv[k * IN_F + fi];
      }
    }
  }
  *(ushort4*)(X0 + node * IN_F + 4 * lane) = o;
#pragma unroll
  for (int k = 0; k < K_MIX; k++)
    for (int off = 32; off; off >>= 1) gsum[k] += __shfl_xor(gsum[k], off, 64);
  if (lane == 0) {
    float lg[K_MIX], mx = -1e30f;
#pragma unroll
    for (int k = 0; k < K_MIX; k++) {
      lg[k] = logp[k] - 0.5f * gsum[k];
      mx = fmaxf(mx, lg[k]);
    }
    float se = 0.f;
#pragma unroll
    for (int k = 0; k < K_MIX; k++) { lg[k] = expf(lg[k] - mx); se += lg[k]; }
    float inv = 1.f / se;
#pragma unroll
    for (int k = 0; k < K_MIX; k++) gamma[node * K_MIX + k] = lg[k] * inv;
  }
}

// ---- fused 3-way SpMM: A@x0 | A@m | A2@m  (one wave per node) ----------------
// Depth-4 software pipeline: 4 row gathers in flight per wave, fixed reg slots.
__global__ void k_spmm(const unsigned short* __restrict__ X0,
                       const int* __restrict__ startofs, const int* __restrict__ deg,
                       const float* __restrict__ dinv, const int* __restrict__ csr_col,
                       const float* __restrict__ csr_w, unsigned short* __restrict__ G,
                       float* __restrict__ sArr) {
  int t = threadIdx.x;
  int node = blockIdx.x * 4 + (t >> 6);
  if (node >= N_NODES) return;
  int lane = t & 63;
  int fo = 4 * lane;
  float ax[4] = {0, 0, 0, 0}, am[4] = {0, 0, 0, 0}, am2[4] = {0, 0, 0, 0};
  float ssum = 0.f;
  float ws = dinv[node];
  ws = ws * ws;
  int st = startofs[node];
  int total = deg[node] + 1;  // virtual edge 0 = self loop
  ushort4 zero4 = {0, 0, 0, 0};
  ushort4 b0 = zero4, b1 = zero4, b2 = zero4, b3 = zero4;
  float w0 = 0.f, w1 = 0.f, w2 = 0.f, w3 = 0.f;
  // prologue: virtual idx 0..3
  b0 = *(const ushort4*)(X0 + node * IN_F + fo); w0 = ws;
  if (1 < total) { int c = csr_col[st];     w1 = csr_w[st];     b1 = *(const ushort4*)(X0 + c * IN_F + fo); }
  if (2 < total) { int c = csr_col[st + 1]; w2 = csr_w[st + 1]; b2 = *(const ushort4*)(X0 + c * IN_F + fo); }
  if (3 < total) { int c = csr_col[st + 2]; w3 = csr_w[st + 2]; b3 = *(const ushort4*)(X0 + c * IN_F + fo); }

#define CONSUME(B, W)                                           \
  {                                                             \
    float wv = (W), wv2 = wv * wv;                              \
    ssum += wv;                                                 \
    const unsigned short* xp = (const unsigned short*)&(B);     \
    _Pragma("unroll")                                           \
    for (int j = 0; j < 4; j++) {                               \
      float xf = bf2f(xp[j]);                                   \
      bool nn = (xf != xf);                                     \
      ax[j] = fmaf(wv, nn ? 0.f : xf, ax[j]);                   \
      am[j] += nn ? wv : 0.f;                                   \
      am2[j] += nn ? wv2 : 0.f;                                 \
    }                                                           \
  }

  for (int base = 0; base < total; base += 4) {
    CONSUME(b0, w0);
    if (base + 4 < total) { int c = csr_col[st + base + 3]; w0 = csr_w[st + base + 3];
                            b0 = *(const ushort4*)(X0 + c * IN_F + fo); }
    else { w0 = 0.f; b0 = zero4; }
    CONSUME(b1, w1);
    if (base + 5 < total) { int c = csr_col[st + base + 4]; w1 = csr_w[st + base + 4];
                            b1 = *(const ushort4*)(X0 + c * IN_F + fo); }
    else { w1 = 0.f; b1 = zero4; }
    CONSUME(b2, w2);
    if (base + 6 < total) { int c = csr_col[st + base + 5]; w2 = csr_w[st + base + 5];
                            b2 = *(const ushort4*)(X0 + c * IN_F + fo); }
    else { w2 = 0.f; b2 = zero4; }
    CONSUME(b3, w3);
    if (base + 7 < total) { int c = csr_col[st + base + 6]; w3 = csr_w[st + base + 6];
                            b3 = *(const ushort4*)(X0 + c * IN_F + fo); }
    else { w3 = 0.f; b3 = zero4; }
  }
#undef CONSUME

  ushort4 o;
  o.x = f2bf(ax[0]); o.y = f2bf(ax[1]); o.z = f2bf(ax[2]); o.w = f2bf(ax[3]);
  *(ushort4*)(G + node * 768 + fo) = o;
  o.x = f2bf(am[0]); o.y = f2bf(am[1]); o.z = f2bf(am[2]); o.w = f2bf(am[3]);
  *(ushort4*)(G + node * 768 + 256 + fo) = o;
  o.x = f2bf(am2[0]); o.y = f2bf(am2[1]); o.z = f2bf(am2[2]); o.w = f2bf(am2[3]);
  *(ushort4*)(G + node * 768 + 512 + fo) = o;
  if (lane == 0) sArr[node] = ssum;
}

// ---- MFMA GEMM, LDS-staged (m97-style): T = (G slice) @ B_jt, bf16 out -------
__global__ __launch_bounds__(256) void k_gemm(const unsigned short* __restrict__ G,
                                              const unsigned short* __restrict__ Bt,
                                              unsigned short* __restrict__ T) {
  __shared__ char Als[128 * 64 * 2];  // 16 KB
  __shared__ char Bls[128 * 64 * 2];  // 16 KB
  int mt = blockIdx.x, jt = blockIdx.y;
  int aoff = (jt == 0) ? 0 : (jt <= 5 ? 256 : 512);
  int t = threadIdx.x, wave = t >> 6, lane = t & 63;
  int wr = wave >> 1, wc = wave & 1;
  int quad = lane >> 4, l16 = lane & 15;
  const unsigned short* Bp = Bt + (size_t)jt * 32768;

  floatx4 acc[4][4];
  floatx4 z = {0.f, 0.f, 0.f, 0.f};
#pragma unroll
  for (int mi = 0; mi < 4; mi++)
#pragma unroll
    for (int ni = 0; ni < 4; ni++) acc[mi][ni] = z;

  for (int k0 = 0; k0 < 256; k0 += 64) {
    __syncthreads();
#pragma unroll
    for (int i = 0; i < 4; i++) {
      int f = i * 256 + t;
      int r = f >> 3, cchunk = f & 7;
      int sw = cchunk ^ (r & 7);
      int gr = mt * 128 + r;
      if (gr >= N_NODES) gr = N_NODES - 1;
      *(uint4*)(Als + r * 128 + sw * 16) =
          *(const uint4*)(G + (size_t)gr * 768 + aoff + k0 + cchunk * 8);
      *(uint4*)(Bls + r * 128 + sw * 16) =
          *(const uint4*)(Bp + (size_t)r * 256 + k0 + cchunk * 8);
    }
    __syncthreads();
#pragma unroll
    for (int ks = 0; ks < 2; ks++) {
      int cc = ks * 4 + quad;
      short8 a[4], b[4];
#pragma unroll
      for (int mi = 0; mi < 4; mi++) {
        int r = wr * 64 + mi * 16 + l16;
        a[mi] = *(const short8*)(Als + r * 128 + (cc ^ (r & 7)) * 16);
      }
#pragma unroll
      for (int ni = 0; ni < 4; ni++) {
        int r = wc * 64 + ni * 16 + l16;
        b[ni] = *(const short8*)(Bls + r * 128 + (cc ^ (r & 7)) * 16);
      }
#pragma unroll
      for (int mi = 0; mi < 4; mi++)
#pragma unroll
        for (int ni = 0; ni < 4; ni++)
          acc[mi][ni] = __builtin_amdgcn_mfma_f32_16x16x32_bf16(a[mi], b[ni], acc[mi][ni], 0, 0, 0);
    }
  }
#pragma unroll
  for (int mi = 0; mi < 4; mi++)
#pragma unroll
    for (int ni = 0; ni < 4; ni++) {
      int gc = jt * 128 + wc * 64 + ni * 16 + l16;
#pragma unroll
      for (int reg = 0; reg < 4; reg++) {
        int gr = mt * 128 + wr * 64 + mi * 16 + quad * 4 + reg;
        if (gr < N_NODES) T[(size_t)gr * TC + gc] = f2bf(acc[mi][ni][reg]);
      }
    }
}

// ---------------- epilogue: Ex_relu + gamma-weighted combine ----------------
__global__ void k_final(const unsigned short* __restrict__ T, const float* __restrict__ gamma,
                        const float* __restrict__ sArr, const float* __restrict__ bias,
                        float* __restrict__ out) {
  int t = threadIdx.x;
  int node = blockIdx.x * 4 + (t >> 6);
  if (node >= N_NODES) return;
  int lane = t & 63;
  int o0 = 2 * lane;
  float g[K_MIX];
#pragma unroll
  for (int k = 0; k < K_MIX; k++) g[k] = gamma[node * K_MIX + k];
  float sv = sArr[node];
  float b0 = bias[o0], b1 = bias[o0 + 1];
  const unsigned short* Tr = T + (size_t)node * TC;
  unsigned int c0u = *(const unsigned int*)(Tr + o0);
  float cx0 = bf2f(c0u), cx1 = bf2f(c0u >> 16);
  float a0 = 0.f, a1 = 0.f;
#pragma unroll
  for (int k = 0; k < K_MIX; k++) {
    unsigned int tm = *(const unsigned int*)(Tr + 128 * (1 + k) + o0);
    unsigned int tv = *(const unsigned int*)(Tr + 128 * (6 + k) + o0);
    float mu0 = cx0 + bf2f(tm) + b0 * sv;
    float mu1 = cx1 + bf2f(tm >> 16) + b1 * sv;
    a0 += g[k] * exrelu(mu0, bf2f(tv));
    a1 += g[k] * exrelu(mu1, bf2f(tv >> 16));
  }
  float2 ov = {a0, a1};
  *(float2*)(out + (size_t)node * OUT_F + o0) = ov;
}

extern "C" void kernel_launch(void* const* d_in, const int* in_sizes, int n_in,
                              void* d_out, int out_size, void* d_ws, size_t ws_size,
                              hipStream_t stream) {
  const float* x = (const float*)d_in[0];
  const int* ei = (const int*)d_in[1];
  const float* logp = (const float*)d_in[2];
  const float* means = (const float*)d_in[3];
  const float* lvar = (const float*)d_in[4];
  const float* W = (const float*)d_in[5];
  const float* bias = (const float*)d_in[6];
  float* out = (float*)d_out;
  const int* row = ei;
  const int* col = ei + N_EDGES;

  char* p = (char*)d_ws;
  auto alloc = [&](size_t bytes) -> char* {
    char* q = p;
    p += (bytes + 255) & ~((size_t)255);
    return q;
  };
  int* deg = (int*)alloc(N_NODES * 4);
  float* dinv = (float*)alloc(N_NODES * 4);
  int* startofs = (int*)alloc(N_NODES * 4);
  int* cursor = (int*)alloc(N_NODES * 4);
  int* bsums = (int*)alloc(128 * 4);
  int* csr_col = (int*)alloc((size_t)N_EDGES * 4);
  float* csr_w = (float*)alloc((size_t)N_EDGES * 4);
  float* gamma = (float*)alloc((size_t)N_NODES * K_MIX * 4);
  float* sArr = (float*)alloc(N_NODES * 4);
  unsigned short* Bt = (unsigned short*)alloc((size_t)NT * 128 * 256 * 2);
  unsigned short* X0 = (unsigned short*)alloc((size_t)N_NODES * IN_F * 2);
  unsigned short* G = (unsigned short*)alloc((size_t)N_NODES * 768 * 2);
  unsigned short* T = (unsigned short*)alloc((size_t)N_NODES * TC * 2);

  hipMemsetAsync(deg, 0, N_NODES * 4, stream);
  k_deg<<<(N_EDGES + 255) / 256, 256, 0, stream>>>(row, deg);
  k_scan1<<<79, 256, 0, stream>>>(deg, startofs, bsums, dinv);
  k_scan2<<<1, 128, 0, stream>>>(bsums, 79);
  k_scan3<<<79, 256, 0, stream>>>(startofs, cursor, bsums);
  k_scatter<<<(N_EDGES + 255) / 256, 256, 0, stream>>>(row, col, dinv, cursor, csr_col, csr_w);
  k_buildB<<<(NT * 128 * 256) / 256, 256, 0, stream>>>(W, means, lvar, Bt);
  k_prepx<<<N_NODES / 4, 256, 0, stream>>>(x, logp, means, lvar, X0, gamma);
  k_spmm<<<N_NODES / 4, 256, 0, stream>>>(X0, startofs, deg, dinv, csr_col, csr_w, G, sArr);
  k_gemm<<<dim3((N_NODES + 127) / 128, NT), 256, 0, stream>>>(G, Bt, T);
  k_final<<<N_NODES / 4, 256, 0, stream>>>(T, gamma, sArr, bias, out);
}

// Round 9
// 230.128 us; speedup vs baseline: 1.2751x; 1.0289x over previous
//
#include <hip/hip_runtime.h>
#include <stdint.h>

#define N_NODES 20000
#define N_EDGES 320000
#define K_MIX 5
#define IN_F 256
#define OUT_F 128
#define NT 11              /* 1 + 2K column tiles of 128 */
#define TC (NT * OUT_F)    /* 1408 */

typedef __attribute__((ext_vector_type(8))) short short8;
typedef __attribute__((ext_vector_type(4))) float floatx4;

__device__ __forceinline__ float bf2f(unsigned int u) {
  union { unsigned int i; float f; } v;
  v.i = (u & 0xffffu) << 16;
  return v.f;
}
__device__ __forceinline__ unsigned short f2bf(float f) {
  union { float f; unsigned int i; } v;
  v.f = f;
  unsigned int x = v.i;
  unsigned int r = (x + 0x7fffu + ((x >> 16) & 1u)) >> 16;
  return (unsigned short)r;
}

// E[relu(X)], X ~ N(mu, sig) (sig is variance). Fast erf: A&S 7.1.26 reusing
// exp(-w^2/2) (== exp(-x^2) for x = w/sqrt2). |erf err| < 1.5e-7.
__device__ __forceinline__ float exrelu(float mu, float sig) {
  if (sig < 1e-30f) return fmaxf(mu, 0.f);
  float ss = sqrtf(sig);
  float w = mu / ss;
  float e = __expf(-0.5f * w * w);
  float axv = fabsf(w) * 0.70710678118654752f;
  float t = 1.f / (1.f + 0.3275911f * axv);
  float poly = t * (0.254829592f +
              t * (-0.284496736f +
              t * (1.421413741f +
              t * (-1.453152027f + t * 1.061405429f))));
  float erfv = 1.f - poly * e;
  erfv = copysignf(erfv, w);
  return ss * (e * 0.3989422804014327f + 0.5f * w * (1.f + erfv));
}

// ---------------- degree ----------------
__global__ void k_deg(const int* __restrict__ row, int* __restrict__ deg) {
  int t = blockIdx.x * 256 + threadIdx.x;
  if (t < N_EDGES) atomicAdd(&deg[row[t]], 1);
}

// ---------------- CSR build: scan (+dinv fused) + scatter ----------------
__global__ void k_scan1(const int* __restrict__ deg, int* __restrict__ startofs,
                        int* __restrict__ bsums, float* __restrict__ dinv) {
  __shared__ int sd[256];
  int t = threadIdx.x;
  int i = blockIdx.x * 256 + t;
  int v = (i < N_NODES) ? deg[i] : 0;
  if (i < N_NODES) dinv[i] = rsqrtf((float)(v + 1));  // +1 self-loop
  sd[t] = v;
  __syncthreads();
  for (int off = 1; off < 256; off <<= 1) {
    int u = (t >= off) ? sd[t - off] : 0;
    __syncthreads();
    sd[t] += u;
    __syncthreads();
  }
  if (i < N_NODES) startofs[i] = sd[t] - v;
  if (t == 255) bsums[blockIdx.x] = sd[255];
}

__global__ void k_scan2(int* __restrict__ bsums, int nb) {
  __shared__ int sd[128];
  int t = threadIdx.x;
  int v = (t < nb) ? bsums[t] : 0;
  sd[t] = v;
  __syncthreads();
  for (int off = 1; off < 128; off <<= 1) {
    int u = (t >= off) ? sd[t - off] : 0;
    __syncthreads();
    sd[t] += u;
    __syncthreads();
  }
  if (t < nb) bsums[t] = sd[t] - v;  // exclusive
}

__global__ void k_scan3(int* __restrict__ startofs, int* __restrict__ cursor,
                        const int* __restrict__ bsums) {
  int i = blockIdx.x * 256 + threadIdx.x;
  if (i < N_NODES) {
    int s0 = startofs[i] + bsums[blockIdx.x];
    startofs[i] = s0;
    cursor[i] = s0;
  }
}

__global__ void k_scatter(const int* __restrict__ row, const int* __restrict__ col,
                          const float* __restrict__ dinv, int* __restrict__ cursor,
                          int* __restrict__ csr_col, float* __restrict__ csr_w) {
  int t = blockIdx.x * 256 + threadIdx.x;
  if (t < N_EDGES) {
    int r = row[t], c = col[t];
    int p = atomicAdd(&cursor[r], 1);
    csr_col[p] = c;
    csr_w[p] = dinv[r] * dinv[c];
  }
}

// ---------------- B-matrix build: Bt[j][n][k] bf16 (transposed for MFMA B) ----
__global__ void k_buildB(const float* __restrict__ W, const float* __restrict__ means,
                         const float* __restrict__ logvars, unsigned short* __restrict__ Bt) {
  int idx = blockIdx.x * 256 + threadIdx.x;  // < 11*128*256
  int j = idx >> 15;
  int rem = idx & 32767;
  int n = rem >> 8;
  int kk = rem & 255;
  float wv = W[kk * OUT_F + n];
  float val;
  if (j == 0) val = wv;                                        // W
  else if (j <= 5) val = means[(j - 1) * IN_F + kk] * wv;      // means_k * W
  else val = expf(logvars[(j - 6) * IN_F + kk]) * wv * wv;     // var_k * W^2
  Bt[idx] = f2bf(val);
}

// ---- prep: pack x -> bf16 X0 (NaN marker 0x7FC0 for missing) + gamma ---------
__global__ void k_prepx(const float* __restrict__ x, const float* __restrict__ logp,
                        const float* __restrict__ means, const float* __restrict__ logvars,
                        unsigned short* __restrict__ X0, float* __restrict__ gamma) {
  __shared__ float s_mean[K_MIX * IN_F];
  __shared__ float s_rv[K_MIX * IN_F];
  int t = threadIdx.x;
  for (int j = t; j < K_MIX * IN_F; j += 256) {
    s_mean[j] = means[j];
    s_rv[j] = expf(-logvars[j]);  // 1/var
  }
  __syncthreads();
  int node = blockIdx.x * 4 + (t >> 6);
  if (node >= N_NODES) return;
  int lane = t & 63;
  float4 xv = *(const float4*)(x + (size_t)node * IN_F + 4 * lane);
  float xf[4] = {xv.x, xv.y, xv.z, xv.w};
  float gsum[K_MIX] = {0, 0, 0, 0, 0};
  ushort4 o;
  unsigned short* op = (unsigned short*)&o;
#pragma unroll
  for (int j = 0; j < 4; j++) {
    bool nn = (xf[j] != xf[j]);
    op[j] = nn ? (unsigned short)0x7FC0 : f2bf(xf[j]);
    if (!nn) {
      int fi = 4 * lane + j;
#pragma unroll
      for (int k = 0; k < K_MIX; k++) {
        float d = xf[j] - s_mean[k * IN_F + fi];
        gsum[k] += d * d * s_rv[k * IN_F + fi];
      }
    }
  }
  *(ushort4*)(X0 + node * IN_F + 4 * lane) = o;
#pragma unroll
  for (int k = 0; k < K_MIX; k++)
    for (int off = 32; off; off >>= 1) gsum[k] += __shfl_xor(gsum[k], off, 64);
  if (lane == 0) {
    float lg[K_MIX], mx = -1e30f;
#pragma unroll
    for (int k = 0; k < K_MIX; k++) {
      lg[k] = logp[k] - 0.5f * gsum[k];
      mx = fmaxf(mx, lg[k]);
    }
    float se = 0.f;
#pragma unroll
    for (int k = 0; k < K_MIX; k++) { lg[k] = expf(lg[k] - mx); se += lg[k]; }
    float inv = 1.f / se;
#pragma unroll
    for (int k = 0; k < K_MIX; k++) gamma[node * K_MIX + k] = lg[k] * inv;
  }
}

// ---- fused 3-way SpMM: A@x0 | A@m | A2@m  (ONE 64-thread BLOCK per node) -----
// node = blockIdx.x is block-uniform -> compiler scalarizes CSR loads (s_load)
// and row-base address math; vector offset is loop-invariant. Depth-8 pipeline.
__global__ __launch_bounds__(64) void k_spmm(const unsigned short* __restrict__ X0,
                       const int* __restrict__ startofs, const int* __restrict__ deg,
                       const float* __restrict__ dinv, const int* __restrict__ csr_col,
                       const float* __restrict__ csr_w, unsigned short* __restrict__ G,
                       float* __restrict__ sArr) {
  int node = blockIdx.x;
  int lane = threadIdx.x;
  int fo = 4 * lane;
  float ax[4] = {0, 0, 0, 0}, am[4] = {0, 0, 0, 0}, am2[4] = {0, 0, 0, 0};
  float ssum = 0.f;
  float ws = dinv[node];
  ws = ws * ws;
  int st = startofs[node];
  int total = deg[node] + 1;  // virtual idx 0 = self loop, v>=1 -> edge v-1
  ushort4 zero4 = {0, 0, 0, 0};
  ushort4 B0 = zero4, B1 = zero4, B2 = zero4, B3 = zero4,
          B4 = zero4, B5 = zero4, B6 = zero4, B7 = zero4;
  float W0 = 0.f, W1 = 0.f, W2 = 0.f, W3 = 0.f,
        W4 = 0.f, W5 = 0.f, W6 = 0.f, W7 = 0.f;
  // prologue: fill slots with virtual idx 0..7
  B0 = *(const ushort4*)(X0 + node * IN_F + fo); W0 = ws;
#define PFILL(S)                                                      \
  if (S < total) {                                                    \
    int c = csr_col[st + (S - 1)];                                    \
    W##S = csr_w[st + (S - 1)];                                       \
    B##S = *(const ushort4*)(X0 + c * IN_F + fo);                     \
  }
  PFILL(1) PFILL(2) PFILL(3) PFILL(4) PFILL(5) PFILL(6) PFILL(7)
#undef PFILL

#define STEP(S)                                                       \
  if (W##S != 0.f) {                                                  \
    float wv = W##S, wv2 = wv * wv;                                   \
    ssum += wv;                                                       \
    const unsigned short* xp = (const unsigned short*)&B##S;          \
    _Pragma("unroll")                                                 \
    for (int j = 0; j < 4; j++) {                                     \
      float xf = bf2f(xp[j]);                                         \
      bool nn = (xf != xf);                                           \
      ax[j] = fmaf(wv, nn ? 0.f : xf, ax[j]);                         \
      am[j] += nn ? wv : 0.f;                                         \
      am2[j] += nn ? wv2 : 0.f;                                       \
    }                                                                 \
  }                                                                   \
  if (base + 8 + S < total) {                                         \
    int c = csr_col[st + base + 7 + S];                               \
    W##S = csr_w[st + base + 7 + S];                                  \
    B##S = *(const ushort4*)(X0 + c * IN_F + fo);                     \
  } else {                                                            \
    W##S = 0.f;                                                       \
  }

  for (int base = 0; base < total; base += 8) {
    STEP(0) STEP(1) STEP(2) STEP(3) STEP(4) STEP(5) STEP(6) STEP(7)
  }
#undef STEP

  ushort4 o;
  o.x = f2bf(ax[0]); o.y = f2bf(ax[1]); o.z = f2bf(ax[2]); o.w = f2bf(ax[3]);
  *(ushort4*)(G + node * 768 + fo) = o;
  o.x = f2bf(am[0]); o.y = f2bf(am[1]); o.z = f2bf(am[2]); o.w = f2bf(am[3]);
  *(ushort4*)(G + node * 768 + 256 + fo) = o;
  o.x = f2bf(am2[0]); o.y = f2bf(am2[1]); o.z = f2bf(am2[2]); o.w = f2bf(am2[3]);
  *(ushort4*)(G + node * 768 + 512 + fo) = o;
  if (lane == 0) sArr[node] = ssum;
}

// ---- MFMA GEMM, LDS-staged (m97-style): T = (G slice) @ B_jt, bf16 out -------
__global__ __launch_bounds__(256) void k_gemm(const unsigned short* __restrict__ G,
                                              const unsigned short* __restrict__ Bt,
                                              unsigned short* __restrict__ T) {
  __shared__ char Als[128 * 64 * 2];  // 16 KB
  __shared__ char Bls[128 * 64 * 2];  // 16 KB
  int mt = blockIdx.x, jt = blockIdx.y;
  int aoff = (jt == 0) ? 0 : (jt <= 5 ? 256 : 512);
  int t = threadIdx.x, wave = t >> 6, lane = t & 63;
  int wr = wave >> 1, wc = wave & 1;
  int quad = lane >> 4, l16 = lane & 15;
  const unsigned short* Bp = Bt + (size_t)jt * 32768;

  floatx4 acc[4][4];
  floatx4 z = {0.f, 0.f, 0.f, 0.f};
#pragma unroll
  for (int mi = 0; mi < 4; mi++)
#pragma unroll
    for (int ni = 0; ni < 4; ni++) acc[mi][ni] = z;

  for (int k0 = 0; k0 < 256; k0 += 64) {
    __syncthreads();
#pragma unroll
    for (int i = 0; i < 4; i++) {
      int f = i * 256 + t;
      int r = f >> 3, cchunk = f & 7;
      int sw = cchunk ^ (r & 7);
      int gr = mt * 128 + r;
      if (gr >= N_NODES) gr = N_NODES - 1;
      *(uint4*)(Als + r * 128 + sw * 16) =
          *(const uint4*)(G + (size_t)gr * 768 + aoff + k0 + cchunk * 8);
      *(uint4*)(Bls + r * 128 + sw * 16) =
          *(const uint4*)(Bp + (size_t)r * 256 + k0 + cchunk * 8);
    }
    __syncthreads();
#pragma unroll
    for (int ks = 0; ks < 2; ks++) {
      int cc = ks * 4 + quad;
      short8 a[4], b[4];
#pragma unroll
      for (int mi = 0; mi < 4; mi++) {
        int r = wr * 64 + mi * 16 + l16;
        a[mi] = *(const short8*)(Als + r * 128 + (cc ^ (r & 7)) * 16);
      }
#pragma unroll
      for (int ni = 0; ni < 4; ni++) {
        int r = wc * 64 + ni * 16 + l16;
        b[ni] = *(const short8*)(Bls + r * 128 + (cc ^ (r & 7)) * 16);
      }
#pragma unroll
      for (int mi = 0; mi < 4; mi++)
#pragma unroll
        for (int ni = 0; ni < 4; ni++)
          acc[mi][ni] = __builtin_amdgcn_mfma_f32_16x16x32_bf16(a[mi], b[ni], acc[mi][ni], 0, 0, 0);
    }
  }
#pragma unroll
  for (int mi = 0; mi < 4; mi++)
#pragma unroll
    for (int ni = 0; ni < 4; ni++) {
      int gc = jt * 128 + wc * 64 + ni * 16 + l16;
#pragma unroll
      for (int reg = 0; reg < 4; reg++) {
        int gr = mt * 128 + wr * 64 + mi * 16 + quad * 4 + reg;
        if (gr < N_NODES) T[(size_t)gr * TC + gc] = f2bf(acc[mi][ni][reg]);
      }
    }
}

// ---------------- epilogue: Ex_relu + gamma-weighted combine ----------------
__global__ void k_final(const unsigned short* __restrict__ T, const float* __restrict__ gamma,
                        const float* __restrict__ sArr, const float* __restrict__ bias,
                        float* __restrict__ out) {
  int t = threadIdx.x;
  int node = blockIdx.x * 4 + (t >> 6);
  if (node >= N_NODES) return;
  int lane = t & 63;
  int o0 = 2 * lane;
  float g[K_MIX];
#pragma unroll
  for (int k = 0; k < K_MIX; k++) g[k] = gamma[node * K_MIX + k];
  float sv = sArr[node];
  float b0 = bias[o0], b1 = bias[o0 + 1];
  const unsigned short* Tr = T + (size_t)node * TC;
  unsigned int c0u = *(const unsigned int*)(Tr + o0);
  float cx0 = bf2f(c0u), cx1 = bf2f(c0u >> 16);
  float a0 = 0.f, a1 = 0.f;
#pragma unroll
  for (int k = 0; k < K_MIX; k++) {
    unsigned int tm = *(const unsigned int*)(Tr + 128 * (1 + k) + o0);
    unsigned int tv = *(const unsigned int*)(Tr + 128 * (6 + k) + o0);
    float mu0 = cx0 + bf2f(tm) + b0 * sv;
    float mu1 = cx1 + bf2f(tm >> 16) + b1 * sv;
    a0 += g[k] * exrelu(mu0, bf2f(tv));
    a1 += g[k] * exrelu(mu1, bf2f(tv >> 16));
  }
  float2 ov = {a0, a1};
  *(float2*)(out + (size_t)node * OUT_F + o0) = ov;
}

extern "C" void kernel_launch(void* const* d_in, const int* in_sizes, int n_in,
                              void* d_out, int out_size, void* d_ws, size_t ws_size,
                              hipStream_t stream) {
  const float* x = (const float*)d_in[0];
  const int* ei = (const int*)d_in[1];
  const float* logp = (const float*)d_in[2];
  const float* means = (const float*)d_in[3];
  const float* lvar = (const float*)d_in[4];
  const float* W = (const float*)d_in[5];
  const float* bias = (const float*)d_in[6];
  float* out = (float*)d_out;
  const int* row = ei;
  const int* col = ei + N_EDGES;

  char* p = (char*)d_ws;
  auto alloc = [&](size_t bytes) -> char* {
    char* q = p;
    p += (bytes + 255) & ~((size_t)255);
    return q;
  };
  int* deg = (int*)alloc(N_NODES * 4);
  float* dinv = (float*)alloc(N_NODES * 4);
  int* startofs = (int*)alloc(N_NODES * 4);
  int* cursor = (int*)alloc(N_NODES * 4);
  int* bsums = (int*)alloc(128 * 4);
  int* csr_col = (int*)alloc((size_t)N_EDGES * 4);
  float* csr_w = (float*)alloc((size_t)N_EDGES * 4);
  float* gamma = (float*)alloc((size_t)N_NODES * K_MIX * 4);
  float* sArr = (float*)alloc(N_NODES * 4);
  unsigned short* Bt = (unsigned short*)alloc((size_t)NT * 128 * 256 * 2);
  unsigned short* X0 = (unsigned short*)alloc((size_t)N_NODES * IN_F * 2);
  unsigned short* G = (unsigned short*)alloc((size_t)N_NODES * 768 * 2);
  unsigned short* T = (unsigned short*)alloc((size_t)N_NODES * TC * 2);

  hipMemsetAsync(deg, 0, N_NODES * 4, stream);
  k_deg<<<(N_EDGES + 255) / 256, 256, 0, stream>>>(row, deg);
  k_scan1<<<79, 256, 0, stream>>>(deg, startofs, bsums, dinv);
  k_scan2<<<1, 128, 0, stream>>>(bsums, 79);
  k_scan3<<<79, 256, 0, stream>>>(startofs, cursor, bsums);
  k_scatter<<<(N_EDGES + 255) / 256, 256, 0, stream>>>(row, col, dinv, cursor, csr_col, csr_w);
  k_buildB<<<(NT * 128 * 256) / 256, 256, 0, stream>>>(W, means, lvar, Bt);
  k_prepx<<<N_NODES / 4, 256, 0, stream>>>(x, logp, means, lvar, X0, gamma);
  k_spmm<<<N_NODES, 64, 0, stream>>>(X0, startofs, deg, dinv, csr_col, csr_w, G, sArr);
  k_gemm<<<dim3((N_NODES + 127) / 128, NT), 256, 0, stream>>>(G, Bt, T);
  k_final<<<N_NODES / 4, 256, 0, stream>>>(T, gamma, sArr, bias, out);
}